// Round 11
// baseline (259.780 us; speedup 1.0000x reference)
//
#include <hip/hip_runtime.h>
#include <math.h>

#define N_NODES 32768
#define E_EDGES 262144
#define NFEAT   512
#define NHID    256
#define NCLASS  40
#define EPSV    0.1f
#define VLEN    1024
#define WLEN    32
#define KEEP0   256
#define KEEP1   128

typedef __attribute__((ext_vector_type(8)))  short bf16x8;
typedef __attribute__((ext_vector_type(4)))  float f32x4;
typedef __attribute__((ext_vector_type(16))) float f32x16;
typedef __attribute__((ext_vector_type(4)))  int   i32x4;
typedef __attribute__((ext_vector_type(8)))  unsigned short us8;

__device__ inline unsigned short f2bf(float f) {
    unsigned int u = __builtin_bit_cast(unsigned int, f);
    return (unsigned short)((u + 0x7FFFu + ((u >> 16) & 1u)) >> 16);
}
__device__ inline float bf2f(unsigned short h) {
    unsigned int u = ((unsigned int)h) << 16;
    return __builtin_bit_cast(float, u);
}

__device__ inline void split_pair(float a, float b, unsigned& hi, unsigned& lo) {
    unsigned ua = __builtin_bit_cast(unsigned, a);
    unsigned ub = __builtin_bit_cast(unsigned, b);
    unsigned ha = ua & 0xFFFF0000u, hb = ub & 0xFFFF0000u;
    hi = (ha >> 16) | hb;
    float la = a - __builtin_bit_cast(float, ha);
    float lb = b - __builtin_bit_cast(float, hb);
    unsigned ula = __builtin_bit_cast(unsigned, la);
    unsigned ulb = __builtin_bit_cast(unsigned, lb);
    lo = (ula >> 16) | (ulb & 0xFFFF0000u);
}

__device__ __forceinline__ void gload16(const void* g, void* l) {
    __builtin_amdgcn_global_load_lds(
        (const __attribute__((address_space(1))) unsigned int*)g,
        (__attribute__((address_space(3))) unsigned int*)l,
        16, 0, 0);
}

// ---------------- init: top=1, cnt=0, cur=0 ----------------
__global__ void init_kernel(float* __restrict__ top, int* __restrict__ cnt,
                            int* __restrict__ cur) {
    int i = blockIdx.x * 256 + threadIdx.x;
    top[i] = 1.0f;
    cnt[i] = 0;
    cur[i] = 0;
}

// ---------------- count in-degree ----------------
__global__ void count_kernel(const int* __restrict__ dst, int* __restrict__ cnt) {
    int e = blockIdx.x * 256 + threadIdx.x;
    atomicAdd(&cnt[dst[e]], 1);
}

// ---------------- exclusive prefix sum over 32768 counts (1 block) ----------------
__global__ __launch_bounds__(1024) void scan_kernel(const int* __restrict__ cnt,
                                                    int* __restrict__ off) {
    __shared__ int part[1024];
    int t = threadIdx.x;
    int base = t * 32;
    int local[32];
    int s = 0;
#pragma unroll
    for (int i = 0; i < 32; ++i) { local[i] = s; s += cnt[base + i]; }
    part[t] = s;
    __syncthreads();
    for (int d = 1; d < 1024; d <<= 1) {
        int v = (t >= d) ? part[t - d] : 0;
        __syncthreads();
        part[t] += v;
        __syncthreads();
    }
    int prev = (t == 0) ? 0 : part[t - 1];
#pragma unroll
    for (int i = 0; i < 32; ++i) off[base + i] = prev + local[i];
    if (t == 1023) off[N_NODES] = prev + s;
}

// ---------------- scatter edges into CSR slots ----------------
__global__ void scatter_kernel(const int* __restrict__ src, const int* __restrict__ dst,
                               const float* __restrict__ eattr,
                               const int* __restrict__ off, int* __restrict__ cur,
                               int* __restrict__ csr_src, float* __restrict__ csr_w) {
    int e = blockIdx.x * 256 + threadIdx.x;
    int d = dst[e];
    int p = atomicAdd(&cur[d], 1);
    int k = off[d] + p;
    csr_src[k] = src[e];
    csr_w[k]   = eattr[e];
}

// ---------------- split Ws into bf16 hi/lo ----------------
__global__ void wsplit_kernel(const float* __restrict__ Ws,
                              unsigned short* __restrict__ Whi,
                              unsigned short* __restrict__ Wlo) {
    int i = blockIdx.x * 256 + threadIdx.x;
    float4 v = ((const float4*)Ws)[i];
    ushort4 hh, ll;
    hh.x = f2bf(v.x); ll.x = f2bf(v.x - bf2f(hh.x));
    hh.y = f2bf(v.y); ll.y = f2bf(v.y - bf2f(hh.y));
    hh.z = f2bf(v.z); ll.z = f2bf(v.z - bf2f(hh.z));
    hh.w = f2bf(v.w); ll.w = f2bf(v.w - bf2f(hh.w));
    ((ushort4*)Whi)[i] = hh;
    ((ushort4*)Wlo)[i] = ll;
}

// ---------------- h0 = relu(x @ Ws^T + b): 8 waves, 2-buffer, COUNTED vmcnt ----------------
// Per wave per tile: 4 gload16. Loop: vmcnt(4) [next tile's loads stay in flight] ->
// s_barrier -> compute buf[kt&1] -> s_barrier -> stage(kt+2) into the freed buffer.
// Per-wave vmcnt + barrier = collective readiness (T3/T4, m218). Never drain to 0 mid-loop.
__global__ __launch_bounds__(512, 4) void gemm_mfma8w(
        const float* __restrict__ x, const unsigned short* __restrict__ Whi,
        const unsigned short* __restrict__ Wlo, const float* __restrict__ b,
        float* __restrict__ h0) {
    __shared__ float          As[2][128 * 32];
    __shared__ unsigned short Bhs[2][128 * 32];
    __shared__ unsigned short Bls[2][128 * 32];

    int tid  = threadIdx.x;
    int wid  = tid >> 6;
    int lane = tid & 63;
    int l31  = lane & 31;
    int khalf = lane >> 5;
    int wr = wid >> 1, wc = wid & 1;

    int wg = (blockIdx.x & 7) * 64 + (blockIdx.x >> 3);
    int row0 = (wg >> 1) * 128;
    int col0 = (wg & 1) * 128;

    f32x16 acc[2];
#pragma unroll
    for (int nr = 0; nr < 2; ++nr)
#pragma unroll
        for (int e = 0; e < 16; ++e) acc[nr][e] = 0.f;

    auto stage = [&](int kt, int buf) {
#pragma unroll
        for (int i = 0; i < 2; ++i) {
            int c    = wid * 2 + i;
            int d    = c * 1024 + lane * 16;
            int row  = d >> 7;
            int off  = d & 127;
            int loff = off ^ ((row & 7) << 4);
            const float* src = &x[(size_t)(row0 + row) * NFEAT + kt * 32 + (loff >> 2)];
            gload16(src, &As[buf][c * 256]);
        }
        {
            int d     = wid * 1024 + lane * 16;
            int wrow  = d >> 6;
            int slot  = (d >> 4) & 3;
            int lslot = slot ^ ((wrow >> 1) & 3);
            size_t so = (size_t)(col0 + wrow) * NFEAT + kt * 32 + lslot * 8;
            gload16(&Whi[so], &Bhs[buf][wid * 512]);
            gload16(&Wlo[so], &Bls[buf][wid * 512]);
        }
    };

    stage(0, 0);
    stage(1, 1);

    for (int kt = 0; kt < NFEAT / 32; ++kt) {
        int cur = kt & 1;
        if (kt < NFEAT / 32 - 1) {
            asm volatile("s_waitcnt vmcnt(4)" ::: "memory");   // current tile done; next in flight
        } else {
            asm volatile("s_waitcnt vmcnt(0)" ::: "memory");
        }
        __builtin_amdgcn_sched_barrier(0);
        __builtin_amdgcn_s_barrier();
        __builtin_amdgcn_sched_barrier(0);

        const float*          Ab  = As[cur];
        const unsigned short* Bhb = Bhs[cur];
        const unsigned short* Blb = Bls[cur];

#pragma unroll
        for (int s = 0; s < 2; ++s) {
            int rt = wr * 32 + l31;
            const char* rowp = (const char*)(Ab + rt * 32);
            int lo0 = s * 64 + khalf * 32;
            int sw  = (rt & 7) << 4;
            f32x4 va = *(const f32x4*)(rowp + (lo0 ^ sw));
            f32x4 vb = *(const f32x4*)(rowp + ((lo0 + 16) ^ sw));
            unsigned h01, h23, h45, h67, l01, l23, l45, l67;
            split_pair(va[0], va[1], h01, l01);
            split_pair(va[2], va[3], h23, l23);
            split_pair(vb[0], vb[1], h45, l45);
            split_pair(vb[2], vb[3], h67, l67);
            i32x4 hv = {(int)h01, (int)h23, (int)h45, (int)h67};
            i32x4 lv = {(int)l01, (int)l23, (int)l45, (int)l67};
            bf16x8 ah  = __builtin_bit_cast(bf16x8, hv);
            bf16x8 alo = __builtin_bit_cast(bf16x8, lv);

            bf16x8 bh[2], bl[2];
#pragma unroll
            for (int nr = 0; nr < 2; ++nr) {
                int ct = wc * 64 + nr * 32 + l31;
                int lb = s * 32 + khalf * 16;
                int ob = lb ^ (((ct >> 1) & 3) << 4);
                bh[nr] = *(const bf16x8*)((const char*)(Bhb + ct * 32) + ob);
                bl[nr] = *(const bf16x8*)((const char*)(Blb + ct * 32) + ob);
            }
#pragma unroll
            for (int nr = 0; nr < 2; ++nr) {
                acc[nr] = __builtin_amdgcn_mfma_f32_32x32x16_bf16(ah,  bh[nr], acc[nr], 0, 0, 0);
                acc[nr] = __builtin_amdgcn_mfma_f32_32x32x16_bf16(ah,  bl[nr], acc[nr], 0, 0, 0);
                acc[nr] = __builtin_amdgcn_mfma_f32_32x32x16_bf16(alo, bh[nr], acc[nr], 0, 0, 0);
            }
        }
        __builtin_amdgcn_sched_barrier(0);
        __builtin_amdgcn_s_barrier();      // all waves finished reading buf cur
        if (kt + 2 < NFEAT / 32) stage(kt + 2, cur);   // refill freed buffer; stays in flight
    }

    // epilogue: D col=lane&31, row=(reg&3)+8*(reg>>2)+4*(lane>>5)
#pragma unroll
    for (int nr = 0; nr < 2; ++nr) {
        int col = col0 + wc * 64 + nr * 32 + l31;
        float bias = b[col];
#pragma unroll
        for (int r = 0; r < 16; ++r) {
            int rowt = (r & 3) + 8 * (r >> 2) + 4 * khalf;
            int row = row0 + wr * 32 + rowt;
            float v = acc[nr][r] + bias;
            h0[(size_t)row * NHID + col] = v > 0.f ? v : 0.f;
        }
    }
}

// ---------------- dots (layer 0 only), grid-stride ----------------
__global__ __launch_bounds__(256, 8) void dots_kernel(
        const float* __restrict__ h, const float* __restrict__ attl,
        const float* __restrict__ attr_, float* __restrict__ al, float* __restrict__ ar) {
    int sub  = threadIdx.x >> 6;
    int lane = threadIdx.x & 63;
    float4 lv = *(const float4*)&attl[lane * 4];
    float4 rv = *(const float4*)&attr_[lane * 4];
    for (int node = blockIdx.x * 4 + sub; node < N_NODES; node += 2048 * 4) {
        float4 hv = *(const float4*)&h[(size_t)node * NHID + lane * 4];
        float sl = hv.x * lv.x + hv.y * lv.y + hv.z * lv.z + hv.w * lv.w;
        float sr = hv.x * rv.x + hv.y * rv.y + hv.z * rv.z + hv.w * rv.w;
#pragma unroll
        for (int off = 32; off; off >>= 1) {
            sl += __shfl_down(sl, off);
            sr += __shfl_down(sr, off);
        }
        if (lane == 0) { al[node] = sl; ar[node] = sr; }
    }
}

// ---------------- layer-0 gather, grid-stride, unconditional 8-wide ----------------
__global__ __launch_bounds__(256, 8) void gather_l0(
        const int* __restrict__ csr_src, const int* __restrict__ off,
        const float* __restrict__ csr_w,
        const float* __restrict__ al0, const float* __restrict__ ar0,
        const float* __restrict__ h0,
        float* __restrict__ h_out, float* __restrict__ nrm,
        const float* __restrict__ attl1, const float* __restrict__ attr1,
        float* __restrict__ al1, float* __restrict__ ar1) {
    int sub  = threadIdx.x >> 6;
    int lane = threadIdx.x & 63;
    for (int node = blockIdx.x * 4 + sub; node < N_NODES; node += 2048 * 4) {
        size_t base = (size_t)node * NHID + lane * 4;
        float arn = ar0[node];
        int k0 = off[node], k1 = off[node + 1];
        float4 a1 = make_float4(0.f, 0.f, 0.f, 0.f);
        float4 a2 = make_float4(0.f, 0.f, 0.f, 0.f);
        for (int cbase = k0; cbase < k1; cbase += 64) {
            int nk = k1 - cbase; if (nk > 64) nk = 64;
            float cv = 0.f; int sv = 0;
            if (lane < nk) {
                int kk = cbase + lane;
                sv = csr_src[kk];
                cv = tanhf(al0[sv] + arn) * csr_w[kk];
            }
            int j = 0;
            for (; j + 7 < nk; j += 8) {
                float c0=__shfl(cv,j),   c1=__shfl(cv,j+1), c2=__shfl(cv,j+2), c3=__shfl(cv,j+3);
                float c4=__shfl(cv,j+4), c5=__shfl(cv,j+5), c6=__shfl(cv,j+6), c7=__shfl(cv,j+7);
                int   s0=__shfl(sv,j),   s1=__shfl(sv,j+1), s2=__shfl(sv,j+2), s3=__shfl(sv,j+3);
                int   s4=__shfl(sv,j+4), s5=__shfl(sv,j+5), s6=__shfl(sv,j+6), s7=__shfl(sv,j+7);
                float4 v0 = *(const float4*)&h0[(size_t)s0 * NHID + lane * 4];
                float4 v1 = *(const float4*)&h0[(size_t)s1 * NHID + lane * 4];
                float4 v2 = *(const float4*)&h0[(size_t)s2 * NHID + lane * 4];
                float4 v3 = *(const float4*)&h0[(size_t)s3 * NHID + lane * 4];
                float4 v4 = *(const float4*)&h0[(size_t)s4 * NHID + lane * 4];
                float4 v5 = *(const float4*)&h0[(size_t)s5 * NHID + lane * 4];
                float4 v6 = *(const float4*)&h0[(size_t)s6 * NHID + lane * 4];
                float4 v7 = *(const float4*)&h0[(size_t)s7 * NHID + lane * 4];
                a1.x += c0*v0.x + c1*v1.x + c2*v2.x + c3*v3.x;
                a1.y += c0*v0.y + c1*v1.y + c2*v2.y + c3*v3.y;
                a1.z += c0*v0.z + c1*v1.z + c2*v2.z + c3*v3.z;
                a1.w += c0*v0.w + c1*v1.w + c2*v2.w + c3*v3.w;
                a2.x += c4*v4.x + c5*v5.x + c6*v6.x + c7*v7.x;
                a2.y += c4*v4.y + c5*v5.y + c6*v6.y + c7*v7.y;
                a2.z += c4*v4.z + c5*v5.z + c6*v6.z + c7*v7.z;
                a2.w += c4*v4.w + c5*v5.w + c6*v6.w + c7*v7.w;
            }
            for (; j + 3 < nk; j += 4) {
                float c0=__shfl(cv,j), c1=__shfl(cv,j+1), c2=__shfl(cv,j+2), c3=__shfl(cv,j+3);
                int   s0=__shfl(sv,j), s1=__shfl(sv,j+1), s2=__shfl(sv,j+2), s3=__shfl(sv,j+3);
                float4 v0 = *(const float4*)&h0[(size_t)s0 * NHID + lane * 4];
                float4 v1 = *(const float4*)&h0[(size_t)s1 * NHID + lane * 4];
                float4 v2 = *(const float4*)&h0[(size_t)s2 * NHID + lane * 4];
                float4 v3 = *(const float4*)&h0[(size_t)s3 * NHID + lane * 4];
                a1.x += c0*v0.x + c1*v1.x + c2*v2.x + c3*v3.x;
                a1.y += c0*v0.y + c1*v1.y + c2*v2.y + c3*v3.y;
                a1.z += c0*v0.z + c1*v1.z + c2*v2.z + c3*v3.z;
                a1.w += c0*v0.w + c1*v1.w + c2*v2.w + c3*v3.w;
            }
            for (; j < nk; ++j) {
                float c = __shfl(cv, j);
                int   s = __shfl(sv, j);
                float4 v = *(const float4*)&h0[(size_t)s * NHID + lane * 4];
                a1.x += c*v.x; a1.y += c*v.y; a1.z += c*v.z; a1.w += c*v.w;
            }
        }
        float4 z = *(const float4*)&h0[base];
        float4 v;
        v.x = a1.x + a2.x + EPSV * z.x;
        v.y = a1.y + a2.y + EPSV * z.y;
        v.z = a1.z + a2.z + EPSV * z.z;
        v.w = a1.w + a2.w + EPSV * z.w;
        *(float4*)&h_out[base] = v;
        float ss = v.x * v.x + v.y * v.y + v.z * v.z + v.w * v.w;
        float4 lv = *(const float4*)&attl1[lane * 4];
        float4 rv = *(const float4*)&attr1[lane * 4];
        float sl = v.x * lv.x + v.y * lv.y + v.z * lv.z + v.w * lv.w;
        float sr = v.x * rv.x + v.y * rv.y + v.z * rv.z + v.w * rv.w;
#pragma unroll
        for (int o = 32; o; o >>= 1) {
            ss += __shfl_down(ss, o);
            sl += __shfl_down(sl, o);
            sr += __shfl_down(sr, o);
        }
        if (lane == 0) { nrm[node] = sqrtf(ss); al1[node] = sl; ar1[node] = sr; }
    }
}

// ---------------- layer-1 gather over survivor list ----------------
__global__ __launch_bounds__(256) void gather_l1(
        const int* __restrict__ surv, const int* __restrict__ csr_src,
        const int* __restrict__ off, const float* __restrict__ csr_w,
        const float* __restrict__ al1, const float* __restrict__ ar1,
        const float* __restrict__ top, const float* __restrict__ h_in,
        const float* __restrict__ h0,
        float* __restrict__ h_out, float* __restrict__ nrm) {
    int node = surv[blockIdx.x * 4 + (threadIdx.x >> 6)];
    int lane = threadIdx.x & 63;
    size_t base = (size_t)node * NHID + lane * 4;
    float arn = ar1[node];
    int k0 = off[node], k1 = off[node + 1];
    float4 acc = make_float4(0.f, 0.f, 0.f, 0.f);
    for (int cbase = k0; cbase < k1; cbase += 64) {
        int nk = k1 - cbase; if (nk > 64) nk = 64;
        float cv = 0.f; int sv = 0;
        if (lane < nk) {
            int kk = cbase + lane;
            sv = csr_src[kk];
            float w = csr_w[kk] * top[sv];
            cv = (w == 0.f) ? 0.f : tanhf(al1[sv] + arn) * w;
        }
        int j = 0;
        for (; j + 3 < nk; j += 4) {
            float c0 = __shfl(cv, j),     c1 = __shfl(cv, j + 1);
            float c2 = __shfl(cv, j + 2), c3 = __shfl(cv, j + 3);
            int   s0 = __shfl(sv, j),     s1 = __shfl(sv, j + 1);
            int   s2 = __shfl(sv, j + 2), s3 = __shfl(sv, j + 3);
            if (c0 != 0.f) { float4 v = *(const float4*)&h_in[(size_t)s0 * NHID + lane * 4];
                acc.x += c0 * v.x; acc.y += c0 * v.y; acc.z += c0 * v.z; acc.w += c0 * v.w; }
            if (c1 != 0.f) { float4 v = *(const float4*)&h_in[(size_t)s1 * NHID + lane * 4];
                acc.x += c1 * v.x; acc.y += c1 * v.y; acc.z += c1 * v.z; acc.w += c1 * v.w; }
            if (c2 != 0.f) { float4 v = *(const float4*)&h_in[(size_t)s2 * NHID + lane * 4];
                acc.x += c2 * v.x; acc.y += c2 * v.y; acc.z += c2 * v.z; acc.w += c2 * v.w; }
            if (c3 != 0.f) { float4 v = *(const float4*)&h_in[(size_t)s3 * NHID + lane * 4];
                acc.x += c3 * v.x; acc.y += c3 * v.y; acc.z += c3 * v.z; acc.w += c3 * v.w; }
        }
        for (; j < nk; ++j) {
            float c = __shfl(cv, j);
            if (c != 0.f) {
                int s = __shfl(sv, j);
                float4 v = *(const float4*)&h_in[(size_t)s * NHID + lane * 4];
                acc.x += c * v.x; acc.y += c * v.y; acc.z += c * v.z; acc.w += c * v.w;
            }
        }
    }
    float4 z = *(const float4*)&h0[base];
    float4 v;
    v.x = acc.x + EPSV * z.x;
    v.y = acc.y + EPSV * z.y;
    v.z = acc.z + EPSV * z.z;
    v.w = acc.w + EPSV * z.w;
    *(float4*)&h_out[base] = v;
    float ss = v.x * v.x + v.y * v.y + v.z * v.z + v.w * v.w;
#pragma unroll
    for (int o = 32; o; o >>= 1) ss += __shfl_down(ss, o);
    if (lane == 0) nrm[node] = sqrtf(ss);
}

// ---------------- per-column stable top-k + deterministic survivor compaction ----------------
__global__ __launch_bounds__(1024) void topk_kernel(
        const float* __restrict__ nrm_in, float* __restrict__ nrm_out,
        float* __restrict__ top, int drop_from, int* __restrict__ surv) {
    __shared__ float s[VLEN];
    int c = blockIdx.x;
    int r = threadIdx.x;
    int idx = r * WLEN + c;
    float v = nrm_in[idx];
    s[r] = v;
    __syncthreads();
    int cnt = 0;
    for (int r2 = 0; r2 < VLEN; ++r2) {
        float v2 = s[r2];
        cnt += (v2 > v) || (v2 == v && r2 < r);
    }
    if (cnt >= drop_from) {
        top[idx] = 0.f;
        nrm_out[idx] = 0.f;
    } else {
        surv[c * drop_from + cnt] = idx;
    }
}

// ---------------- out = h @ We^T + be over the 4096 final survivors ----------------
#define ASTR 40
#define OBSTR 264
__global__ __launch_bounds__(256) void out_mfma_list(
        const int* __restrict__ surv2, const float* __restrict__ h,
        const float* __restrict__ We, const float* __restrict__ be,
        float* __restrict__ out) {
    __shared__ unsigned short Bh[48 * OBSTR];
    __shared__ unsigned short Bl[48 * OBSTR];
    __shared__ unsigned short Ah[64 * ASTR];
    __shared__ unsigned short Al[64 * ASTR];
    __shared__ int sids[64];
    int tid  = threadIdx.x;
    int w    = tid >> 6;
    int lane = tid & 63;
    int m16  = lane & 15;
    int kblk = lane >> 4;

    if (tid < 64) sids[tid] = surv2[blockIdx.x * 64 + tid];

    for (int i = tid; i < 48 * 64; i += 256) {
        int r = i >> 6, k4 = i & 63;
        float4 v = (r < NCLASS) ? *(const float4*)&We[r * NHID + k4 * 4]
                                : make_float4(0.f, 0.f, 0.f, 0.f);
        ushort4 hh, ll;
        hh.x = f2bf(v.x); ll.x = f2bf(v.x - bf2f(hh.x));
        hh.y = f2bf(v.y); ll.y = f2bf(v.y - bf2f(hh.y));
        hh.z = f2bf(v.z); ll.z = f2bf(v.z - bf2f(hh.z));
        hh.w = f2bf(v.w); ll.w = f2bf(v.w - bf2f(hh.w));
        *(ushort4*)&Bh[r * OBSTR + k4 * 4] = hh;
        *(ushort4*)&Bl[r * OBSTR + k4 * 4] = ll;
    }
    __syncthreads();

    f32x4 acc[3];
#pragma unroll
    for (int nr = 0; nr < 3; ++nr)
#pragma unroll
        for (int e = 0; e < 4; ++e) acc[nr][e] = 0.f;

    for (int kt = 0; kt < NHID; kt += 32) {
#pragma unroll
        for (int i = 0; i < 2; ++i) {
            int f = tid + 256 * i;
            int row = f >> 3, k4 = f & 7;
            int node = sids[row];
            float4 v = *(const float4*)&h[(size_t)node * NHID + kt + k4 * 4];
            ushort4 hh, ll;
            hh.x = f2bf(v.x); ll.x = f2bf(v.x - bf2f(hh.x));
            hh.y = f2bf(v.y); ll.y = f2bf(v.y - bf2f(hh.y));
            hh.z = f2bf(v.z); ll.z = f2bf(v.z - bf2f(hh.z));
            hh.w = f2bf(v.w); ll.w = f2bf(v.w - bf2f(hh.w));
            *(ushort4*)&Ah[row * ASTR + k4 * 4] = hh;
            *(ushort4*)&Al[row * ASTR + k4 * 4] = ll;
        }
        __syncthreads();
        int ar_ = w * 16 + m16;
        bf16x8 ah  = *(const bf16x8*)&Ah[ar_ * ASTR + kblk * 8];
        bf16x8 alo = *(const bf16x8*)&Al[ar_ * ASTR + kblk * 8];
#pragma unroll
        for (int nr = 0; nr < 3; ++nr) {
            int br = nr * 16 + m16;
            bf16x8 bh = *(const bf16x8*)&Bh[br * OBSTR + kt + kblk * 8];
            bf16x8 bl = *(const bf16x8*)&Bl[br * OBSTR + kt + kblk * 8];
            acc[nr] = __builtin_amdgcn_mfma_f32_16x16x32_bf16(ah,  bh, acc[nr], 0, 0, 0);
            acc[nr] = __builtin_amdgcn_mfma_f32_16x16x32_bf16(ah,  bl, acc[nr], 0, 0, 0);
            acc[nr] = __builtin_amdgcn_mfma_f32_16x16x32_bf16(alo, bh, acc[nr], 0, 0, 0);
        }
        __syncthreads();
    }
#pragma unroll
    for (int nr = 0; nr < 3; ++nr) {
        int col = nr * 16 + m16;
        if (col < NCLASS) {
            float bias = be[col];
#pragma unroll
            for (int r = 0; r < 4; ++r) {
                int row = w * 16 + kblk * 4 + r;
                int node = sids[row];
                out[(size_t)node * NCLASS + col] = acc[nr][r] + bias;
            }
        }
    }
}

extern "C" void kernel_launch(void* const* d_in, const int* in_sizes, int n_in,
                              void* d_out, int out_size, void* d_ws, size_t ws_size,
                              hipStream_t stream) {
    const float* x     = (const float*)d_in[0];
    const int*   ei    = (const int*)d_in[1];
    const float* eattr = (const float*)d_in[2];
    const float* Ws    = (const float*)d_in[3];
    const float* bs    = (const float*)d_in[4];
    const float* attl  = (const float*)d_in[5];
    const float* attr_ = (const float*)d_in[6];
    const float* We    = (const float*)d_in[7];
    const float* be    = (const float*)d_in[8];
    float* out = (float*)d_out;

    char* ws = (char*)d_ws;
    const size_t HB = (size_t)N_NODES * NHID * sizeof(float);   // 32 MB
    float* hA  = (float*)(ws);
    float* hB  = (float*)(ws + HB);
    float* h0  = (float*)(ws + 2 * HB);
    char* sm = ws + 3 * HB;
    float* al0      = (float*)(sm);               sm += 131072;
    float* ar0      = (float*)(sm);               sm += 131072;
    float* al1      = (float*)(sm);               sm += 131072;
    float* ar1      = (float*)(sm);               sm += 131072;
    float* nrm      = (float*)(sm);               sm += 131072;
    float* top      = (float*)(sm);               sm += 131072;
    int*   cnt      = (int*)(sm);                 sm += 131072;
    int*   cur      = (int*)(sm);                 sm += 131072;
    int*   off      = (int*)(sm);                 sm += 262144;
    int*   csr_src  = (int*)(sm);                 sm += E_EDGES * 4;
    float* csr_w    = (float*)(sm);               sm += E_EDGES * 4;
    int*   surv0    = (int*)(sm);                 sm += KEEP0 * WLEN * 4;
    int*   surv2    = (int*)(sm);                 sm += KEEP1 * WLEN * 4;
    unsigned short* Whi = (unsigned short*)(sm);  sm += NHID * NFEAT * 2;
    unsigned short* Wlo = (unsigned short*)(sm);  sm += NHID * NFEAT * 2;

    const int* srcp = ei;
    const int* dstp = ei + E_EDGES;

    hipMemsetAsync(d_out, 0, (size_t)out_size * sizeof(float), stream);

    init_kernel<<<N_NODES / 256, 256, 0, stream>>>(top, cnt, cur);
    count_kernel<<<E_EDGES / 256, 256, 0, stream>>>(dstp, cnt);
    scan_kernel<<<1, 1024, 0, stream>>>(cnt, off);
    scatter_kernel<<<E_EDGES / 256, 256, 0, stream>>>(srcp, dstp, eattr, off, cur,
                                                      csr_src, csr_w);

    wsplit_kernel<<<(NHID * NFEAT / 4) / 256, 256, 0, stream>>>(Ws, Whi, Wlo);
    gemm_mfma8w<<<(N_NODES / 128) * 2, 512, 0, stream>>>(x, Whi, Wlo, bs, h0);

    dots_kernel<<<2048, 256, 0, stream>>>(h0, attl, attr_, al0, ar0);

    gather_l0<<<2048, 256, 0, stream>>>(csr_src, off, csr_w,
                                        al0, ar0, h0, hA, nrm,
                                        attl + NHID, attr_ + NHID, al1, ar1);
    topk_kernel<<<WLEN, VLEN, 0, stream>>>(nrm, nrm, top, KEEP0, surv0);

    gather_l1<<<(KEEP0 * WLEN) / 4, 256, 0, stream>>>(surv0, csr_src, off, csr_w,
                                                      al1, ar1, top, hA, h0, hB, nrm);
    topk_kernel<<<WLEN, VLEN, 0, stream>>>(nrm, nrm, top, KEEP1, surv2);

    out_mfma_list<<<(KEEP1 * WLEN) / 64, 256, 0, stream>>>(surv2, hB, We, be, out);
}

// Round 12
// 210.442 us; speedup vs baseline: 1.2345x; 1.2345x over previous
//
#include <hip/hip_runtime.h>
#include <math.h>

#define N_NODES 32768
#define E_EDGES 262144
#define NFEAT   512
#define NHID    256
#define NCLASS  40
#define EPSV    0.1f
#define VLEN    1024
#define WLEN    32
#define KEEP0   256
#define KEEP1   128

typedef __attribute__((ext_vector_type(8)))  short bf16x8;
typedef __attribute__((ext_vector_type(4)))  float f32x4;
typedef __attribute__((ext_vector_type(16))) float f32x16;
typedef __attribute__((ext_vector_type(4)))  int   i32x4;
typedef __attribute__((ext_vector_type(8)))  unsigned short us8;

__device__ inline unsigned short f2bf(float f) {
    unsigned int u = __builtin_bit_cast(unsigned int, f);
    return (unsigned short)((u + 0x7FFFu + ((u >> 16) & 1u)) >> 16);
}
__device__ inline float bf2f(unsigned short h) {
    unsigned int u = ((unsigned int)h) << 16;
    return __builtin_bit_cast(float, u);
}

__device__ inline void split_pair(float a, float b, unsigned& hi, unsigned& lo) {
    unsigned ua = __builtin_bit_cast(unsigned, a);
    unsigned ub = __builtin_bit_cast(unsigned, b);
    unsigned ha = ua & 0xFFFF0000u, hb = ub & 0xFFFF0000u;
    hi = (ha >> 16) | hb;
    float la = a - __builtin_bit_cast(float, ha);
    float lb = b - __builtin_bit_cast(float, hb);
    unsigned ula = __builtin_bit_cast(unsigned, la);
    unsigned ulb = __builtin_bit_cast(unsigned, lb);
    lo = (ula >> 16) | (ulb & 0xFFFF0000u);
}

__device__ __forceinline__ void gload16(const void* g, void* l) {
    __builtin_amdgcn_global_load_lds(
        (const __attribute__((address_space(1))) unsigned int*)g,
        (__attribute__((address_space(3))) unsigned int*)l,
        16, 0, 0);
}

// ---------------- fused prep: top/cnt/cur init + Ws split + zero d_out ----------------
// range-partitioned flat id; ranges are 256-aligned so branches are block-uniform.
__global__ __launch_bounds__(256) void prep_kernel(
        float* __restrict__ top, int* __restrict__ cnt, int* __restrict__ cur,
        const float* __restrict__ Ws, unsigned short* __restrict__ Whi,
        unsigned short* __restrict__ Wlo, float4* __restrict__ outz) {
    int i = blockIdx.x * 256 + threadIdx.x;
    if (i < N_NODES) {
        top[i] = 1.0f; cnt[i] = 0; cur[i] = 0;
    } else if (i < 2 * N_NODES) {
        int j = i - N_NODES;                    // float4 index over Ws (32768)
        float4 v = ((const float4*)Ws)[j];
        ushort4 hh, ll;
        hh.x = f2bf(v.x); ll.x = f2bf(v.x - bf2f(hh.x));
        hh.y = f2bf(v.y); ll.y = f2bf(v.y - bf2f(hh.y));
        hh.z = f2bf(v.z); ll.z = f2bf(v.z - bf2f(hh.z));
        hh.w = f2bf(v.w); ll.w = f2bf(v.w - bf2f(hh.w));
        ((ushort4*)Whi)[j] = hh;
        ((ushort4*)Wlo)[j] = ll;
    } else {
        int j = i - 2 * N_NODES;                // float4 index over out (327680)
        outz[j] = make_float4(0.f, 0.f, 0.f, 0.f);
    }
}
#define PREP_BLOCKS ((N_NODES + N_NODES + (N_NODES * NCLASS / 4)) / 256)   // 1536

// ---------------- count in-degree ----------------
__global__ void count_kernel(const int* __restrict__ dst, int* __restrict__ cnt) {
    int e = blockIdx.x * 256 + threadIdx.x;
    atomicAdd(&cnt[dst[e]], 1);
}

// ---------------- exclusive prefix sum over 32768 counts (1 block) ----------------
__global__ __launch_bounds__(1024) void scan_kernel(const int* __restrict__ cnt,
                                                    int* __restrict__ off) {
    __shared__ int part[1024];
    int t = threadIdx.x;
    int base = t * 32;
    int local[32];
    int s = 0;
#pragma unroll
    for (int i = 0; i < 32; ++i) { local[i] = s; s += cnt[base + i]; }
    part[t] = s;
    __syncthreads();
    for (int d = 1; d < 1024; d <<= 1) {
        int v = (t >= d) ? part[t - d] : 0;
        __syncthreads();
        part[t] += v;
        __syncthreads();
    }
    int prev = (t == 0) ? 0 : part[t - 1];
#pragma unroll
    for (int i = 0; i < 32; ++i) off[base + i] = prev + local[i];
    if (t == 1023) off[N_NODES] = prev + s;
}

// ---------------- scatter edges into CSR slots ----------------
__global__ void scatter_kernel(const int* __restrict__ src, const int* __restrict__ dst,
                               const float* __restrict__ eattr,
                               const int* __restrict__ off, int* __restrict__ cur,
                               int* __restrict__ csr_src, float* __restrict__ csr_w) {
    int e = blockIdx.x * 256 + threadIdx.x;
    int d = dst[e];
    int p = atomicAdd(&cur[d], 1);
    int k = off[d] + p;
    csr_src[k] = src[e];
    csr_w[k]   = eattr[e];
}

// ---------------- h0 = relu(x @ Ws^T + b): 8 waves, 2-buffer (R10 form) ----------------
__global__ __launch_bounds__(512, 4) void gemm_mfma8w(
        const float* __restrict__ x, const unsigned short* __restrict__ Whi,
        const unsigned short* __restrict__ Wlo, const float* __restrict__ b,
        float* __restrict__ h0) {
    __shared__ float          As[2][128 * 32];
    __shared__ unsigned short Bhs[2][128 * 32];
    __shared__ unsigned short Bls[2][128 * 32];

    int tid  = threadIdx.x;
    int wid  = tid >> 6;
    int lane = tid & 63;
    int l31  = lane & 31;
    int khalf = lane >> 5;
    int wr = wid >> 1, wc = wid & 1;

    int wg = (blockIdx.x & 7) * 64 + (blockIdx.x >> 3);
    int row0 = (wg >> 1) * 128;
    int col0 = (wg & 1) * 128;

    f32x16 acc[2];
#pragma unroll
    for (int nr = 0; nr < 2; ++nr)
#pragma unroll
        for (int e = 0; e < 16; ++e) acc[nr][e] = 0.f;

    auto stage = [&](int kt, int buf) {
#pragma unroll
        for (int i = 0; i < 2; ++i) {
            int c    = wid * 2 + i;
            int d    = c * 1024 + lane * 16;
            int row  = d >> 7;
            int off  = d & 127;
            int loff = off ^ ((row & 7) << 4);
            const float* src = &x[(size_t)(row0 + row) * NFEAT + kt * 32 + (loff >> 2)];
            gload16(src, &As[buf][c * 256]);
        }
        {
            int d     = wid * 1024 + lane * 16;
            int wrow  = d >> 6;
            int slot  = (d >> 4) & 3;
            int lslot = slot ^ ((wrow >> 1) & 3);
            size_t so = (size_t)(col0 + wrow) * NFEAT + kt * 32 + lslot * 8;
            gload16(&Whi[so], &Bhs[buf][wid * 512]);
            gload16(&Wlo[so], &Bls[buf][wid * 512]);
        }
    };

    stage(0, 0);
    __syncthreads();

    for (int kt = 0; kt < NFEAT / 32; ++kt) {
        int cur = kt & 1;
        if (kt + 1 < NFEAT / 32) stage(kt + 1, cur ^ 1);

        const float*          Ab  = As[cur];
        const unsigned short* Bhb = Bhs[cur];
        const unsigned short* Blb = Bls[cur];

#pragma unroll
        for (int s = 0; s < 2; ++s) {
            int rt = wr * 32 + l31;
            const char* rowp = (const char*)(Ab + rt * 32);
            int lo0 = s * 64 + khalf * 32;
            int sw  = (rt & 7) << 4;
            f32x4 va = *(const f32x4*)(rowp + (lo0 ^ sw));
            f32x4 vb = *(const f32x4*)(rowp + ((lo0 + 16) ^ sw));
            unsigned h01, h23, h45, h67, l01, l23, l45, l67;
            split_pair(va[0], va[1], h01, l01);
            split_pair(va[2], va[3], h23, l23);
            split_pair(vb[0], vb[1], h45, l45);
            split_pair(vb[2], vb[3], h67, l67);
            i32x4 hv = {(int)h01, (int)h23, (int)h45, (int)h67};
            i32x4 lv = {(int)l01, (int)l23, (int)l45, (int)l67};
            bf16x8 ah  = __builtin_bit_cast(bf16x8, hv);
            bf16x8 alo = __builtin_bit_cast(bf16x8, lv);

            bf16x8 bh[2], bl[2];
#pragma unroll
            for (int nr = 0; nr < 2; ++nr) {
                int ct = wc * 64 + nr * 32 + l31;
                int lb = s * 32 + khalf * 16;
                int ob = lb ^ (((ct >> 1) & 3) << 4);
                bh[nr] = *(const bf16x8*)((const char*)(Bhb + ct * 32) + ob);
                bl[nr] = *(const bf16x8*)((const char*)(Blb + ct * 32) + ob);
            }
#pragma unroll
            for (int nr = 0; nr < 2; ++nr) {
                acc[nr] = __builtin_amdgcn_mfma_f32_32x32x16_bf16(ah,  bh[nr], acc[nr], 0, 0, 0);
                acc[nr] = __builtin_amdgcn_mfma_f32_32x32x16_bf16(ah,  bl[nr], acc[nr], 0, 0, 0);
                acc[nr] = __builtin_amdgcn_mfma_f32_32x32x16_bf16(alo, bh[nr], acc[nr], 0, 0, 0);
            }
        }
        __syncthreads();
    }

#pragma unroll
    for (int nr = 0; nr < 2; ++nr) {
        int col = col0 + wc * 64 + nr * 32 + l31;
        float bias = b[col];
#pragma unroll
        for (int r = 0; r < 16; ++r) {
            int rowt = (r & 3) + 8 * (r >> 2) + 4 * khalf;
            int row = row0 + wr * 32 + rowt;
            float v = acc[nr][r] + bias;
            h0[(size_t)row * NHID + col] = v > 0.f ? v : 0.f;
        }
    }
}

// ---------------- dots (layer 0 only) ----------------
__global__ __launch_bounds__(256) void dots_kernel(
        const float* __restrict__ h, const float* __restrict__ attl,
        const float* __restrict__ attr_, float* __restrict__ al, float* __restrict__ ar) {
    int node = blockIdx.x * 4 + (threadIdx.x >> 6);
    int lane = threadIdx.x & 63;
    float4 hv = *(const float4*)&h[(size_t)node * NHID + lane * 4];
    float4 lv = *(const float4*)&attl[lane * 4];
    float4 rv = *(const float4*)&attr_[lane * 4];
    float sl = hv.x * lv.x + hv.y * lv.y + hv.z * lv.z + hv.w * lv.w;
    float sr = hv.x * rv.x + hv.y * rv.y + hv.z * rv.z + hv.w * rv.w;
#pragma unroll
    for (int off = 32; off; off >>= 1) {
        sl += __shfl_down(sl, off);
        sr += __shfl_down(sr, off);
    }
    if (lane == 0) { al[node] = sl; ar[node] = sr; }
}

// ---------------- layer-0 gather (R10 form): unconditional 8-wide, 2 acc chains ----------------
__global__ __launch_bounds__(256) void gather_l0(
        const int* __restrict__ csr_src, const int* __restrict__ off,
        const float* __restrict__ csr_w,
        const float* __restrict__ al0, const float* __restrict__ ar0,
        const float* __restrict__ h0,
        float* __restrict__ h_out, float* __restrict__ nrm,
        const float* __restrict__ attl1, const float* __restrict__ attr1,
        float* __restrict__ al1, float* __restrict__ ar1) {
    int node = blockIdx.x * 4 + (threadIdx.x >> 6);
    int lane = threadIdx.x & 63;
    size_t base = (size_t)node * NHID + lane * 4;
    float arn = ar0[node];
    int k0 = off[node], k1 = off[node + 1];
    float4 a1 = make_float4(0.f, 0.f, 0.f, 0.f);
    float4 a2 = make_float4(0.f, 0.f, 0.f, 0.f);
    for (int cbase = k0; cbase < k1; cbase += 64) {
        int nk = k1 - cbase; if (nk > 64) nk = 64;
        float cv = 0.f; int sv = 0;
        if (lane < nk) {
            int kk = cbase + lane;
            sv = csr_src[kk];
            cv = tanhf(al0[sv] + arn) * csr_w[kk];
        }
        int j = 0;
        for (; j + 7 < nk; j += 8) {
            float c0=__shfl(cv,j),   c1=__shfl(cv,j+1), c2=__shfl(cv,j+2), c3=__shfl(cv,j+3);
            float c4=__shfl(cv,j+4), c5=__shfl(cv,j+5), c6=__shfl(cv,j+6), c7=__shfl(cv,j+7);
            int   s0=__shfl(sv,j),   s1=__shfl(sv,j+1), s2=__shfl(sv,j+2), s3=__shfl(sv,j+3);
            int   s4=__shfl(sv,j+4), s5=__shfl(sv,j+5), s6=__shfl(sv,j+6), s7=__shfl(sv,j+7);
            float4 v0 = *(const float4*)&h0[(size_t)s0 * NHID + lane * 4];
            float4 v1 = *(const float4*)&h0[(size_t)s1 * NHID + lane * 4];
            float4 v2 = *(const float4*)&h0[(size_t)s2 * NHID + lane * 4];
            float4 v3 = *(const float4*)&h0[(size_t)s3 * NHID + lane * 4];
            float4 v4 = *(const float4*)&h0[(size_t)s4 * NHID + lane * 4];
            float4 v5 = *(const float4*)&h0[(size_t)s5 * NHID + lane * 4];
            float4 v6 = *(const float4*)&h0[(size_t)s6 * NHID + lane * 4];
            float4 v7 = *(const float4*)&h0[(size_t)s7 * NHID + lane * 4];
            a1.x += c0*v0.x + c1*v1.x + c2*v2.x + c3*v3.x;
            a1.y += c0*v0.y + c1*v1.y + c2*v2.y + c3*v3.y;
            a1.z += c0*v0.z + c1*v1.z + c2*v2.z + c3*v3.z;
            a1.w += c0*v0.w + c1*v1.w + c2*v2.w + c3*v3.w;
            a2.x += c4*v4.x + c5*v5.x + c6*v6.x + c7*v7.x;
            a2.y += c4*v4.y + c5*v5.y + c6*v6.y + c7*v7.y;
            a2.z += c4*v4.z + c5*v5.z + c6*v6.z + c7*v7.z;
            a2.w += c4*v4.w + c5*v5.w + c6*v6.w + c7*v7.w;
        }
        for (; j + 3 < nk; j += 4) {
            float c0=__shfl(cv,j), c1=__shfl(cv,j+1), c2=__shfl(cv,j+2), c3=__shfl(cv,j+3);
            int   s0=__shfl(sv,j), s1=__shfl(sv,j+1), s2=__shfl(sv,j+2), s3=__shfl(sv,j+3);
            float4 v0 = *(const float4*)&h0[(size_t)s0 * NHID + lane * 4];
            float4 v1 = *(const float4*)&h0[(size_t)s1 * NHID + lane * 4];
            float4 v2 = *(const float4*)&h0[(size_t)s2 * NHID + lane * 4];
            float4 v3 = *(const float4*)&h0[(size_t)s3 * NHID + lane * 4];
            a1.x += c0*v0.x + c1*v1.x + c2*v2.x + c3*v3.x;
            a1.y += c0*v0.y + c1*v1.y + c2*v2.y + c3*v3.y;
            a1.z += c0*v0.z + c1*v1.z + c2*v2.z + c3*v3.z;
            a1.w += c0*v0.w + c1*v1.w + c2*v2.w + c3*v3.w;
        }
        for (; j < nk; ++j) {
            float c = __shfl(cv, j);
            int   s = __shfl(sv, j);
            float4 v = *(const float4*)&h0[(size_t)s * NHID + lane * 4];
            a1.x += c*v.x; a1.y += c*v.y; a1.z += c*v.z; a1.w += c*v.w;
        }
    }
    float4 z = *(const float4*)&h0[base];
    float4 v;
    v.x = a1.x + a2.x + EPSV * z.x;
    v.y = a1.y + a2.y + EPSV * z.y;
    v.z = a1.z + a2.z + EPSV * z.z;
    v.w = a1.w + a2.w + EPSV * z.w;
    *(float4*)&h_out[base] = v;
    float ss = v.x * v.x + v.y * v.y + v.z * v.z + v.w * v.w;
    float4 lv = *(const float4*)&attl1[lane * 4];
    float4 rv = *(const float4*)&attr1[lane * 4];
    float sl = v.x * lv.x + v.y * lv.y + v.z * lv.z + v.w * lv.w;
    float sr = v.x * rv.x + v.y * rv.y + v.z * rv.z + v.w * rv.w;
#pragma unroll
    for (int o = 32; o; o >>= 1) {
        ss += __shfl_down(ss, o);
        sl += __shfl_down(sl, o);
        sr += __shfl_down(sr, o);
    }
    if (lane == 0) { nrm[node] = sqrtf(ss); al1[node] = sl; ar1[node] = sr; }
}

// ---------------- layer-1 gather over survivor list ----------------
__global__ __launch_bounds__(256) void gather_l1(
        const int* __restrict__ surv, const int* __restrict__ csr_src,
        const int* __restrict__ off, const float* __restrict__ csr_w,
        const float* __restrict__ al1, const float* __restrict__ ar1,
        const float* __restrict__ top, const float* __restrict__ h_in,
        const float* __restrict__ h0,
        float* __restrict__ h_out, float* __restrict__ nrm) {
    int node = surv[blockIdx.x * 4 + (threadIdx.x >> 6)];
    int lane = threadIdx.x & 63;
    size_t base = (size_t)node * NHID + lane * 4;
    float arn = ar1[node];
    int k0 = off[node], k1 = off[node + 1];
    float4 acc = make_float4(0.f, 0.f, 0.f, 0.f);
    for (int cbase = k0; cbase < k1; cbase += 64) {
        int nk = k1 - cbase; if (nk > 64) nk = 64;
        float cv = 0.f; int sv = 0;
        if (lane < nk) {
            int kk = cbase + lane;
            sv = csr_src[kk];
            float w = csr_w[kk] * top[sv];
            cv = (w == 0.f) ? 0.f : tanhf(al1[sv] + arn) * w;
        }
        int j = 0;
        for (; j + 3 < nk; j += 4) {
            float c0 = __shfl(cv, j),     c1 = __shfl(cv, j + 1);
            float c2 = __shfl(cv, j + 2), c3 = __shfl(cv, j + 3);
            int   s0 = __shfl(sv, j),     s1 = __shfl(sv, j + 1);
            int   s2 = __shfl(sv, j + 2), s3 = __shfl(sv, j + 3);
            if (c0 != 0.f) { float4 v = *(const float4*)&h_in[(size_t)s0 * NHID + lane * 4];
                acc.x += c0 * v.x; acc.y += c0 * v.y; acc.z += c0 * v.z; acc.w += c0 * v.w; }
            if (c1 != 0.f) { float4 v = *(const float4*)&h_in[(size_t)s1 * NHID + lane * 4];
                acc.x += c1 * v.x; acc.y += c1 * v.y; acc.z += c1 * v.z; acc.w += c1 * v.w; }
            if (c2 != 0.f) { float4 v = *(const float4*)&h_in[(size_t)s2 * NHID + lane * 4];
                acc.x += c2 * v.x; acc.y += c2 * v.y; acc.z += c2 * v.z; acc.w += c2 * v.w; }
            if (c3 != 0.f) { float4 v = *(const float4*)&h_in[(size_t)s3 * NHID + lane * 4];
                acc.x += c3 * v.x; acc.y += c3 * v.y; acc.z += c3 * v.z; acc.w += c3 * v.w; }
        }
        for (; j < nk; ++j) {
            float c = __shfl(cv, j);
            if (c != 0.f) {
                int s = __shfl(sv, j);
                float4 v = *(const float4*)&h_in[(size_t)s * NHID + lane * 4];
                acc.x += c * v.x; acc.y += c * v.y; acc.z += c * v.z; acc.w += c * v.w;
            }
        }
    }
    float4 z = *(const float4*)&h0[base];
    float4 v;
    v.x = acc.x + EPSV * z.x;
    v.y = acc.y + EPSV * z.y;
    v.z = acc.z + EPSV * z.z;
    v.w = acc.w + EPSV * z.w;
    *(float4*)&h_out[base] = v;
    float ss = v.x * v.x + v.y * v.y + v.z * v.z + v.w * v.w;
#pragma unroll
    for (int o = 32; o; o >>= 1) ss += __shfl_down(ss, o);
    if (lane == 0) nrm[node] = sqrtf(ss);
}

// ---------------- per-column stable top-k, 4 row-chunks per column (128 blocks) ----------------
// block = column c (blockIdx>>2) x chunk (blockIdx&3). Full column staged in LDS;
// each thread ranks one row. Deterministic survivor compaction via rank slot.
__global__ __launch_bounds__(256) void topk_kernel(
        const float* __restrict__ nrm_in, float* __restrict__ nrm_out,
        float* __restrict__ top, int drop_from, int* __restrict__ surv) {
    __shared__ float s[VLEN];
    int c     = blockIdx.x >> 2;
    int chunk = blockIdx.x & 3;
    int t = threadIdx.x;
    for (int r = t; r < VLEN; r += 256) s[r] = nrm_in[r * WLEN + c];
    __syncthreads();
    int r = chunk * 256 + t;
    float v = s[r];
    int cnt = 0;
#pragma unroll 8
    for (int r2 = 0; r2 < VLEN; ++r2) {
        float v2 = s[r2];
        cnt += (v2 > v) || (v2 == v && r2 < r);
    }
    int idx = r * WLEN + c;
    if (cnt >= drop_from) {
        top[idx] = 0.f;
        nrm_out[idx] = 0.f;
    } else {
        surv[c * drop_from + cnt] = idx;
    }
}

// ---------------- out = h @ We^T + be over the 4096 final survivors ----------------
#define ASTR 40
#define OBSTR 264
__global__ __launch_bounds__(256) void out_mfma_list(
        const int* __restrict__ surv2, const float* __restrict__ h,
        const float* __restrict__ We, const float* __restrict__ be,
        float* __restrict__ out) {
    __shared__ unsigned short Bh[48 * OBSTR];
    __shared__ unsigned short Bl[48 * OBSTR];
    __shared__ unsigned short Ah[64 * ASTR];
    __shared__ unsigned short Al[64 * ASTR];
    __shared__ int sids[64];
    int tid  = threadIdx.x;
    int w    = tid >> 6;
    int lane = tid & 63;
    int m16  = lane & 15;
    int kblk = lane >> 4;

    if (tid < 64) sids[tid] = surv2[blockIdx.x * 64 + tid];

    for (int i = tid; i < 48 * 64; i += 256) {
        int r = i >> 6, k4 = i & 63;
        float4 v = (r < NCLASS) ? *(const float4*)&We[r * NHID + k4 * 4]
                                : make_float4(0.f, 0.f, 0.f, 0.f);
        ushort4 hh, ll;
        hh.x = f2bf(v.x); ll.x = f2bf(v.x - bf2f(hh.x));
        hh.y = f2bf(v.y); ll.y = f2bf(v.y - bf2f(hh.y));
        hh.z = f2bf(v.z); ll.z = f2bf(v.z - bf2f(hh.z));
        hh.w = f2bf(v.w); ll.w = f2bf(v.w - bf2f(hh.w));
        *(ushort4*)&Bh[r * OBSTR + k4 * 4] = hh;
        *(ushort4*)&Bl[r * OBSTR + k4 * 4] = ll;
    }
    __syncthreads();

    f32x4 acc[3];
#pragma unroll
    for (int nr = 0; nr < 3; ++nr)
#pragma unroll
        for (int e = 0; e < 4; ++e) acc[nr][e] = 0.f;

    for (int kt = 0; kt < NHID; kt += 32) {
#pragma unroll
        for (int i = 0; i < 2; ++i) {
            int f = tid + 256 * i;
            int row = f >> 3, k4 = f & 7;
            int node = sids[row];
            float4 v = *(const float4*)&h[(size_t)node * NHID + kt + k4 * 4];
            ushort4 hh, ll;
            hh.x = f2bf(v.x); ll.x = f2bf(v.x - bf2f(hh.x));
            hh.y = f2bf(v.y); ll.y = f2bf(v.y - bf2f(hh.y));
            hh.z = f2bf(v.z); ll.z = f2bf(v.z - bf2f(hh.z));
            hh.w = f2bf(v.w); ll.w = f2bf(v.w - bf2f(hh.w));
            *(ushort4*)&Ah[row * ASTR + k4 * 4] = hh;
            *(ushort4*)&Al[row * ASTR + k4 * 4] = ll;
        }
        __syncthreads();
        int ar_ = w * 16 + m16;
        bf16x8 ah  = *(const bf16x8*)&Ah[ar_ * ASTR + kblk * 8];
        bf16x8 alo = *(const bf16x8*)&Al[ar_ * ASTR + kblk * 8];
#pragma unroll
        for (int nr = 0; nr < 3; ++nr) {
            int br = nr * 16 + m16;
            bf16x8 bh = *(const bf16x8*)&Bh[br * OBSTR + kt + kblk * 8];
            bf16x8 bl = *(const bf16x8*)&Bl[br * OBSTR + kt + kblk * 8];
            acc[nr] = __builtin_amdgcn_mfma_f32_16x16x32_bf16(ah,  bh, acc[nr], 0, 0, 0);
            acc[nr] = __builtin_amdgcn_mfma_f32_16x16x32_bf16(ah,  bl, acc[nr], 0, 0, 0);
            acc[nr] = __builtin_amdgcn_mfma_f32_16x16x32_bf16(alo, bh, acc[nr], 0, 0, 0);
        }
        __syncthreads();
    }
#pragma unroll
    for (int nr = 0; nr < 3; ++nr) {
        int col = nr * 16 + m16;
        if (col < NCLASS) {
            float bias = be[col];
#pragma unroll
            for (int r = 0; r < 4; ++r) {
                int row = w * 16 + kblk * 4 + r;
                int node = sids[row];
                out[(size_t)node * NCLASS + col] = acc[nr][r] + bias;
            }
        }
    }
}

extern "C" void kernel_launch(void* const* d_in, const int* in_sizes, int n_in,
                              void* d_out, int out_size, void* d_ws, size_t ws_size,
                              hipStream_t stream) {
    const float* x     = (const float*)d_in[0];
    const int*   ei    = (const int*)d_in[1];
    const float* eattr = (const float*)d_in[2];
    const float* Ws    = (const float*)d_in[3];
    const float* bs    = (const float*)d_in[4];
    const float* attl  = (const float*)d_in[5];
    const float* attr_ = (const float*)d_in[6];
    const float* We    = (const float*)d_in[7];
    const float* be    = (const float*)d_in[8];
    float* out = (float*)d_out;

    char* ws = (char*)d_ws;
    const size_t HB = (size_t)N_NODES * NHID * sizeof(float);   // 32 MB
    float* hA  = (float*)(ws);
    float* hB  = (float*)(ws + HB);
    float* h0  = (float*)(ws + 2 * HB);
    char* sm = ws + 3 * HB;
    float* al0      = (float*)(sm);               sm += 131072;
    float* ar0      = (float*)(sm);               sm += 131072;
    float* al1      = (float*)(sm);               sm += 131072;
    float* ar1      = (float*)(sm);               sm += 131072;
    float* nrm      = (float*)(sm);               sm += 131072;
    float* top      = (float*)(sm);               sm += 131072;
    int*   cnt      = (int*)(sm);                 sm += 131072;
    int*   cur      = (int*)(sm);                 sm += 131072;
    int*   off      = (int*)(sm);                 sm += 262144;
    int*   csr_src  = (int*)(sm);                 sm += E_EDGES * 4;
    float* csr_w    = (float*)(sm);               sm += E_EDGES * 4;
    int*   surv0    = (int*)(sm);                 sm += KEEP0 * WLEN * 4;
    int*   surv2    = (int*)(sm);                 sm += KEEP1 * WLEN * 4;
    unsigned short* Whi = (unsigned short*)(sm);  sm += NHID * NFEAT * 2;
    unsigned short* Wlo = (unsigned short*)(sm);  sm += NHID * NFEAT * 2;

    const int* srcp = ei;
    const int* dstp = ei + E_EDGES;

    prep_kernel<<<PREP_BLOCKS, 256, 0, stream>>>(top, cnt, cur, Ws, Whi, Wlo, (float4*)out);
    count_kernel<<<E_EDGES / 256, 256, 0, stream>>>(dstp, cnt);
    scan_kernel<<<1, 1024, 0, stream>>>(cnt, off);
    scatter_kernel<<<E_EDGES / 256, 256, 0, stream>>>(srcp, dstp, eattr, off, cur,
                                                      csr_src, csr_w);

    gemm_mfma8w<<<(N_NODES / 128) * 2, 512, 0, stream>>>(x, Whi, Wlo, bs, h0);

    dots_kernel<<<N_NODES / 4, 256, 0, stream>>>(h0, attl, attr_, al0, ar0);

    gather_l0<<<N_NODES / 4, 256, 0, stream>>>(csr_src, off, csr_w,
                                               al0, ar0, h0, hA, nrm,
                                               attl + NHID, attr_ + NHID, al1, ar1);
    topk_kernel<<<WLEN * 4, 256, 0, stream>>>(nrm, nrm, top, KEEP0, surv0);

    gather_l1<<<(KEEP0 * WLEN) / 4, 256, 0, stream>>>(surv0, csr_src, off, csr_w,
                                                      al1, ar1, top, hA, h0, hB, nrm);
    topk_kernel<<<WLEN * 4, 256, 0, stream>>>(nrm, nrm, top, KEEP1, surv2);

    out_mfma_list<<<(KEEP1 * WLEN) / 64, 256, 0, stream>>>(surv2, hB, We, be, out);
}